// Round 1
// baseline (1797.988 us; speedup 1.0000x reference)
//
#include <hip/hip_runtime.h>

#define HID 40

// tanh(x) = 1 - 2/(exp(2x)+1), via hardware v_exp_f32 + v_rcp_f32.
// Clamped so exp never overflows (inf/inf -> NaN otherwise).
__device__ __forceinline__ float fast_tanh(float x) {
    x = fminf(fmaxf(x, -15.0f), 15.0f);
    float e = __expf(2.0f * x);                    // v_mul + v_exp_f32
    float r = __builtin_amdgcn_rcpf(e + 1.0f);     // v_add + v_rcp_f32
    return __builtin_fmaf(-2.0f, r, 1.0f);         // v_fma
}

__global__ __launch_bounds__(256) void pinn_mlp_kernel(
    const float* __restrict__ coords,
    const float* __restrict__ W0, const float* __restrict__ b0,
    const float* __restrict__ W1, const float* __restrict__ b1,
    const float* __restrict__ W2, const float* __restrict__ b2,
    const float* __restrict__ W3, const float* __restrict__ b3,
    const float* __restrict__ W4, const float* __restrict__ b4,
    const float* __restrict__ W5, const float* __restrict__ b5,
    const float* __restrict__ W6, const float* __restrict__ b6,
    float* __restrict__ out, int n)
{
    const int idx = blockIdx.x * blockDim.x + threadIdx.x;
    if (idx >= n) return;

    const float x0 = coords[idx * 3 + 0];
    const float x1 = coords[idx * 3 + 1];
    const float x2 = coords[idx * 3 + 2];

    float a[HID];   // current activations
    float c[HID];   // accumulators

    // ---- layer 0: [3] -> [40], weights W0[k*40+j] (row-major fan_in x fan_out)
    #pragma unroll
    for (int j = 0; j < HID; ++j) {
        float s = b0[j];
        s = __builtin_fmaf(x0, W0[0 * HID + j], s);
        s = __builtin_fmaf(x1, W0[1 * HID + j], s);
        s = __builtin_fmaf(x2, W0[2 * HID + j], s);
        a[j] = fast_tanh(s);
    }

    // ---- layers 1..5: [40] -> [40] + tanh
    const float* Ws[5] = { W1, W2, W3, W4, W5 };
    const float* bs[5] = { b1, b2, b3, b4, b5 };
    for (int l = 0; l < 5; ++l) {
        const float* __restrict__ W = Ws[l];
        const float* __restrict__ b = bs[l];
        #pragma unroll
        for (int j = 0; j < HID; ++j) c[j] = b[j];
        #pragma unroll
        for (int k = 0; k < HID; ++k) {
            const float xv = a[k];
            #pragma unroll
            for (int j = 0; j < HID; ++j) {
                c[j] = __builtin_fmaf(xv, W[k * HID + j], c[j]);
            }
        }
        #pragma unroll
        for (int j = 0; j < HID; ++j) a[j] = fast_tanh(c[j]);
    }

    // ---- final layer: [40] -> [3], no activation
    float o0 = b6[0], o1 = b6[1], o2 = b6[2];
    #pragma unroll
    for (int k = 0; k < HID; ++k) {
        const float xv = a[k];
        o0 = __builtin_fmaf(xv, W6[k * 3 + 0], o0);
        o1 = __builtin_fmaf(xv, W6[k * 3 + 1], o1);
        o2 = __builtin_fmaf(xv, W6[k * 3 + 2], o2);
    }

    out[idx * 3 + 0] = o0;
    out[idx * 3 + 1] = o1;
    out[idx * 3 + 2] = o2;
}

extern "C" void kernel_launch(void* const* d_in, const int* in_sizes, int n_in,
                              void* d_out, int out_size, void* d_ws, size_t ws_size,
                              hipStream_t stream)
{
    const float* coords = (const float*)d_in[0];
    const float* W0 = (const float*)d_in[1];  const float* b0 = (const float*)d_in[2];
    const float* W1 = (const float*)d_in[3];  const float* b1 = (const float*)d_in[4];
    const float* W2 = (const float*)d_in[5];  const float* b2 = (const float*)d_in[6];
    const float* W3 = (const float*)d_in[7];  const float* b3 = (const float*)d_in[8];
    const float* W4 = (const float*)d_in[9];  const float* b4 = (const float*)d_in[10];
    const float* W5 = (const float*)d_in[11]; const float* b5 = (const float*)d_in[12];
    const float* W6 = (const float*)d_in[13]; const float* b6 = (const float*)d_in[14];
    float* out = (float*)d_out;

    const int n = in_sizes[0] / 3;  // coords is [N,3]
    const int block = 256;
    const int grid = (n + block - 1) / block;

    pinn_mlp_kernel<<<grid, block, 0, stream>>>(
        coords,
        W0, b0, W1, b1, W2, b2, W3, b3, W4, b4, W5, b5, W6, b6,
        out, n);
}

// Round 2
// 553.968 us; speedup vs baseline: 3.2457x; 3.2457x over previous
//
#include <hip/hip_runtime.h>

#define HID 40

// tanh(x) = 1 - 2/(exp(2x)+1), via hardware v_exp_f32 + v_rcp_f32.
// Clamped so exp never overflows (inf/inf -> NaN otherwise).
__device__ __forceinline__ float fast_tanh(float x) {
    x = fminf(fmaxf(x, -15.0f), 15.0f);
    float e = __expf(2.0f * x);                    // v_mul + v_exp_f32
    float r = __builtin_amdgcn_rcpf(e + 1.0f);     // v_add + v_rcp_f32
    return __builtin_fmaf(-2.0f, r, 1.0f);         // v_fma
}

// One hidden layer: o = tanh(W^T a + b). W is [40][40] row-major (fan_in x fan_out).
// Compile-time-distinct call sites + reference-to-array params force full
// unroll + SROA so a/c/o live in VGPRs (round-1 failure: scratch-resident arrays).
__device__ __forceinline__ void layer40(const float* __restrict__ W,
                                        const float* __restrict__ b,
                                        const float (&a)[HID], float (&o)[HID]) {
    float c[HID];
    #pragma unroll
    for (int j = 0; j < HID; ++j) c[j] = b[j];
    #pragma unroll
    for (int k = 0; k < HID; ++k) {
        const float xv = a[k];
        #pragma unroll
        for (int j = 0; j < HID; ++j) {
            c[j] = __builtin_fmaf(xv, W[k * HID + j], c[j]);  // v_fmac v, s, v
        }
    }
    #pragma unroll
    for (int j = 0; j < HID; ++j) o[j] = fast_tanh(c[j]);
}

__global__ __launch_bounds__(256) void pinn_mlp_kernel(
    const float* __restrict__ coords,
    const float* __restrict__ W0, const float* __restrict__ b0,
    const float* __restrict__ W1, const float* __restrict__ b1,
    const float* __restrict__ W2, const float* __restrict__ b2,
    const float* __restrict__ W3, const float* __restrict__ b3,
    const float* __restrict__ W4, const float* __restrict__ b4,
    const float* __restrict__ W5, const float* __restrict__ b5,
    const float* __restrict__ W6, const float* __restrict__ b6,
    float* __restrict__ out, int n)
{
    const int idx = blockIdx.x * blockDim.x + threadIdx.x;
    if (idx >= n) return;

    const float x0 = coords[idx * 3 + 0];
    const float x1 = coords[idx * 3 + 1];
    const float x2 = coords[idx * 3 + 2];

    float a[HID];
    float t[HID];

    // ---- layer 0: [3] -> [40]
    #pragma unroll
    for (int j = 0; j < HID; ++j) {
        float s = b0[j];
        s = __builtin_fmaf(x0, W0[0 * HID + j], s);
        s = __builtin_fmaf(x1, W0[1 * HID + j], s);
        s = __builtin_fmaf(x2, W0[2 * HID + j], s);
        a[j] = fast_tanh(s);
    }

    // ---- 5 hidden layers, compile-time distinct (no runtime pointer array)
    layer40(W1, b1, a, t);
    layer40(W2, b2, t, a);
    layer40(W3, b3, a, t);
    layer40(W4, b4, t, a);
    layer40(W5, b5, a, t);

    // ---- final layer: [40] -> [3], no activation
    float o0 = b6[0], o1 = b6[1], o2 = b6[2];
    #pragma unroll
    for (int k = 0; k < HID; ++k) {
        const float xv = t[k];
        o0 = __builtin_fmaf(xv, W6[k * 3 + 0], o0);
        o1 = __builtin_fmaf(xv, W6[k * 3 + 1], o1);
        o2 = __builtin_fmaf(xv, W6[k * 3 + 2], o2);
    }

    out[idx * 3 + 0] = o0;
    out[idx * 3 + 1] = o1;
    out[idx * 3 + 2] = o2;
}

extern "C" void kernel_launch(void* const* d_in, const int* in_sizes, int n_in,
                              void* d_out, int out_size, void* d_ws, size_t ws_size,
                              hipStream_t stream)
{
    const float* coords = (const float*)d_in[0];
    const float* W0 = (const float*)d_in[1];  const float* b0 = (const float*)d_in[2];
    const float* W1 = (const float*)d_in[3];  const float* b1 = (const float*)d_in[4];
    const float* W2 = (const float*)d_in[5];  const float* b2 = (const float*)d_in[6];
    const float* W3 = (const float*)d_in[7];  const float* b3 = (const float*)d_in[8];
    const float* W4 = (const float*)d_in[9];  const float* b4 = (const float*)d_in[10];
    const float* W5 = (const float*)d_in[11]; const float* b5 = (const float*)d_in[12];
    const float* W6 = (const float*)d_in[13]; const float* b6 = (const float*)d_in[14];
    float* out = (float*)d_out;

    const int n = in_sizes[0] / 3;  // coords is [N,3]
    const int block = 256;
    const int grid = (n + block - 1) / block;

    pinn_mlp_kernel<<<grid, block, 0, stream>>>(
        coords,
        W0, b0, W1, b1, W2, b2, W3, b3, W4, b4, W5, b5, W6, b6,
        out, n);
}

// Round 3
// 145.824 us; speedup vs baseline: 12.3299x; 3.7989x over previous
//
#include <hip/hip_runtime.h>

// ============================================================================
// 7-layer MLP (3->40x6->3, tanh) via f16 MFMA, transposed-activation chaining.
//
// Layout contracts (gfx950 v_mfma_f32_32x32x16_f16):
//   A (M=32 x K=16): row = lane&31, k = 8*(lane>>5) + i, i=0..7 (f16, 4 VGPRs,
//                    element i at reg i>>1, half i&1)
//   B (K=16 x N=32): col = lane&31, k = 8*(lane>>5) + i   (same packing)
//   D (M=32 x N=32): col = lane&31, row = (reg&3) + 8*(reg>>2) + 4*(lane>>5)
//     [verified: learn_hip m74/m101; dtype-independent]
//
// Activations live as X^T (features x points): D cols = points stay on the
// same lane across layers. Next-layer B needs k = 8h+i per half h=lane>>5;
// D provides features at rows (r&3)+8(r>>2)+4h. We PERMUTE the K-columns of
// every A (weights) so that the pk'd D pairs land exactly in B slots:
//   kappa[j] (k-slot of output-neuron j) =
//     {0,1,2,3, 8,9,10,11, 4,5,6,7, 12,13,14,15,
//      16,17,18,19, 24,25,26,27, 20,21,22,23, 28,29,30,31,
//      32,33,34,35, 40,41,42,43}
// Then B chunk c reg e = cvt_pkrtz(d[2p],d[2p+1]) with p=4c+e — in-lane only.
// Bias = extra A column at k=44 (layer0: k=3) against a constant-1.0 B slot.
// Unused K slots have zero A columns, so garbage B there is harmless.
// ============================================================================

typedef _Float16 f16x8 __attribute__((ext_vector_type(8)));
typedef float    f32x16 __attribute__((ext_vector_type(16)));
typedef unsigned int u32x4 __attribute__((ext_vector_type(4)));

#define NFRAG 35   // L0: 2, L1..5: 6 each, L6: 3.  1 frag = 64 lanes x 16 B

// inverse of kappa: k-slot -> input neuron; -2 = bias slot, -1 = zero pad
__constant__ int INV[48] = {
     0,  1,  2,  3,   8,  9, 10, 11,   4,  5,  6,  7,  12, 13, 14, 15,
    16, 17, 18, 19,  24, 25, 26, 27,  20, 21, 22, 23,  28, 29, 30, 31,
    32, 33, 34, 35,  -1, -1, -1, -1,  36, 37, 38, 39,  -2, -1, -1, -1 };

__global__ void prep_frags(const float* __restrict__ W0, const float* __restrict__ b0,
                           const float* __restrict__ W1, const float* __restrict__ b1,
                           const float* __restrict__ W2, const float* __restrict__ b2,
                           const float* __restrict__ W3, const float* __restrict__ b3,
                           const float* __restrict__ W4, const float* __restrict__ b4,
                           const float* __restrict__ W5, const float* __restrict__ b5,
                           const float* __restrict__ W6, const float* __restrict__ b6,
                           unsigned short* __restrict__ frags)
{
    int tid = blockIdx.x * 256 + threadIdx.x;
    if (tid >= NFRAG * 64) return;
    int frag = tid >> 6, lane = tid & 63;

    int layer, mt, ch;
    if (frag < 2)       { layer = 0; mt = frag; ch = 0; }
    else if (frag < 32) { int t = frag - 2; layer = 1 + t / 6; int r = t % 6; mt = r / 3; ch = r % 3; }
    else                { layer = 6; mt = 0; ch = frag - 32; }

    const float* Ws[7] = { W0, W1, W2, W3, W4, W5, W6 };
    const float* bs[7] = { b0, b1, b2, b3, b4, b5, b6 };
    const float* W = Ws[layer];
    const float* b = bs[layer];
    const int fout = (layer == 6) ? 3 : 40;

    int jout  = mt * 32 + (lane & 31);
    int kbase = ch * 16 + (lane >> 5) * 8;

    unsigned short h[8];
    for (int i = 0; i < 8; ++i) {
        int k = kbase + i;
        float v = 0.0f;
        if (jout < fout) {
            int jin;
            if (layer == 0) jin = (k < 3) ? k : ((k == 3) ? -2 : -1);
            else            jin = INV[k];
            if (jin == -2)     v = b[jout];
            else if (jin >= 0) v = W[jin * fout + jout];
        }
        _Float16 hv = (_Float16)v;
        h[i] = __builtin_bit_cast(unsigned short, hv);
    }
    unsigned short* dst = frags + frag * 512 + lane * 8;
    for (int i = 0; i < 8; ++i) dst[i] = h[i];
}

__device__ __forceinline__ unsigned int pkf16(float a, float b) {
    return __builtin_bit_cast(unsigned int, __builtin_amdgcn_cvt_pkrtz(a, b));
}
// tanh(x) = 1 - 2/(e^{2x}+1); no clamp needed: exp->inf gives rcp->0 -> 1.
__device__ __forceinline__ float th(float x) {
    float e = __expf(2.0f * x);
    return __builtin_fmaf(-2.0f, __builtin_amdgcn_rcpf(e + 1.0f), 1.0f);
}
__device__ __forceinline__ f32x16 zf() {
    f32x16 v;
    #pragma unroll
    for (int i = 0; i < 16; ++i) v[i] = 0.0f;
    return v;
}

#define MFMA __builtin_amdgcn_mfma_f32_32x32x16_f16

// D (+Mtile1 low 4 regs) -> tanh -> f16 pack -> next-layer B fragments
#define ACT(Da, Db) do {                              \
    Bf[0] = pkf16(th(Da[0]),  th(Da[1]));             \
    Bf[1] = pkf16(th(Da[2]),  th(Da[3]));             \
    Bf[2] = pkf16(th(Da[4]),  th(Da[5]));             \
    Bf[3] = pkf16(th(Da[6]),  th(Da[7]));             \
    Bf[4] = pkf16(th(Da[8]),  th(Da[9]));             \
    Bf[5] = pkf16(th(Da[10]), th(Da[11]));            \
    Bf[6] = pkf16(th(Da[12]), th(Da[13]));            \
    Bf[7] = pkf16(th(Da[14]), th(Da[15]));            \
    Bf[8] = pkf16(th(Db[0]),  th(Db[1]));             \
    Bf[9] = pkf16(th(Db[2]),  th(Db[3]));             \
    Bf[10] = PK11;                                    \
    Bf[11] = 0u;                                      \
} while (0)

__global__ __launch_bounds__(256) void mlp_mfma(const float* __restrict__ coords,
                                                const unsigned short* __restrict__ frags,
                                                float* __restrict__ out, int npts)
{
    __shared__ __align__(16) unsigned short sf[NFRAG * 512];
    {   // stage all weight fragments (35 KB) into LDS once per block
        const u32x4* src = (const u32x4*)frags;
        u32x4* dst = (u32x4*)sf;
        for (int i = threadIdx.x; i < NFRAG * 64; i += 256) dst[i] = src[i];
    }
    __syncthreads();

    const int lane = threadIdx.x & 63;
    const int wid  = threadIdx.x >> 6;
    const int p    = (blockIdx.x * 4 + wid) * 32 + (lane & 31);
    const bool valid = (p < npts);

    float c0 = 0.f, c1 = 0.f, c2 = 0.f;
    if (valid) { c0 = coords[p * 3]; c1 = coords[p * 3 + 1]; c2 = coords[p * 3 + 2]; }

    const unsigned int PK11 = pkf16(1.0f, 1.0f);

    unsigned int Bf[12];
    Bf[0] = pkf16(c0, c1);
    Bf[1] = pkf16(c2, 1.0f);
    Bf[2] = 0u; Bf[3] = 0u;

    auto AF = [&](int f) -> f16x8 {
        return ((const f16x8*)sf)[f * 64 + lane];
    };
    auto BF = [&](int c) -> f16x8 {
        u32x4 t = { Bf[4 * c + 0], Bf[4 * c + 1], Bf[4 * c + 2], Bf[4 * c + 3] };
        return __builtin_bit_cast(f16x8, t);
    };

    // ---- layer 0 (K chunk 0 only: coords + bias col at k=3)
    {
        f32x16 D0 = zf(), D1 = zf();
        f16x8 bb = BF(0);
        D0 = MFMA(AF(0), bb, D0, 0, 0, 0);
        D1 = MFMA(AF(1), bb, D1, 0, 0, 0);
        ACT(D0, D1);
    }

    // ---- hidden layers 1..5
    #pragma unroll
    for (int l = 1; l <= 5; ++l) {
        const int fb = 2 + (l - 1) * 6;
        f16x8 bc0 = BF(0), bc1 = BF(1), bc2 = BF(2);
        f32x16 D0 = zf(), D1 = zf();
        D0 = MFMA(AF(fb + 0), bc0, D0, 0, 0, 0);
        D0 = MFMA(AF(fb + 1), bc1, D0, 0, 0, 0);
        D0 = MFMA(AF(fb + 2), bc2, D0, 0, 0, 0);
        D1 = MFMA(AF(fb + 3), bc0, D1, 0, 0, 0);
        D1 = MFMA(AF(fb + 4), bc1, D1, 0, 0, 0);
        D1 = MFMA(AF(fb + 5), bc2, D1, 0, 0, 0);
        ACT(D0, D1);
    }

    // ---- layer 6: [40] -> [3], no tanh. Outputs = rows 0..2 (h=0, regs 0..2)
    {
        f32x16 D0 = zf();
        D0 = MFMA(AF(32), BF(0), D0, 0, 0, 0);
        D0 = MFMA(AF(33), BF(1), D0, 0, 0, 0);
        D0 = MFMA(AF(34), BF(2), D0, 0, 0, 0);
        if (lane < 32 && valid) {
            out[p * 3 + 0] = D0[0];
            out[p * 3 + 1] = D0[1];
            out[p * 3 + 2] = D0[2];
        }
    }
}

extern "C" void kernel_launch(void* const* d_in, const int* in_sizes, int n_in,
                              void* d_out, int out_size, void* d_ws, size_t ws_size,
                              hipStream_t stream)
{
    const float* coords = (const float*)d_in[0];
    const float* W0 = (const float*)d_in[1];  const float* b0 = (const float*)d_in[2];
    const float* W1 = (const float*)d_in[3];  const float* b1 = (const float*)d_in[4];
    const float* W2 = (const float*)d_in[5];  const float* b2 = (const float*)d_in[6];
    const float* W3 = (const float*)d_in[7];  const float* b3 = (const float*)d_in[8];
    const float* W4 = (const float*)d_in[9];  const float* b4 = (const float*)d_in[10];
    const float* W5 = (const float*)d_in[11]; const float* b5 = (const float*)d_in[12];
    const float* W6 = (const float*)d_in[13]; const float* b6 = (const float*)d_in[14];
    float* out = (float*)d_out;

    unsigned short* frags = (unsigned short*)d_ws;   // 35*1024 B = 35 KB

    const int npts = in_sizes[0] / 3;

    prep_frags<<<(NFRAG * 64 + 255) / 256, 256, 0, stream>>>(
        W0, b0, W1, b1, W2, b2, W3, b3, W4, b4, W5, b5, W6, b6, frags);

    const int blocks = (npts + 127) / 128;   // 128 points per block (4 waves x 32)
    mlp_mfma<<<blocks, 256, 0, stream>>>(coords, frags, out, npts);
}

// Round 4
// 120.955 us; speedup vs baseline: 14.8650x; 1.2056x over previous
//
#include <hip/hip_runtime.h>

// ============================================================================
// 7-layer MLP (3->40x6->3, tanh) via f16 MFMA + LDS tanh lookup table.
//
// MFMA layout contracts (gfx950 v_mfma_f32_32x32x16_f16), verified in r3:
//   A (M=32 x K=16): row = lane&31, k = 8*(lane>>5) + i, i=0..7
//   B (K=16 x N=32): col = lane&31, k = 8*(lane>>5) + i   (same packing)
//   D (M=32 x N=32): col = lane&31, row = (reg&3) + 8*(reg>>2) + 4*(lane>>5)
// Activations are X^T (features x points); K-columns of every weight matrix
// are permuted (kappa) so D->B repack is pure in-lane cvt_pkrtz.
//
// tanh via LDS table (r4): hidden-layer weights/biases pre-scaled by 1/h=40
// and a constant K-column worth +192 added, so the MFMA emits the table
// coordinate u = (preact + 4.8)/0.025 directly. Lookup = med3 clamp, fract,
// cvt, ds_read_b64 of {tanh, delta}, fma. 8-way lane replication keeps bank
// conflicts <=4-way on the LGKM pipe (VALU is the bottleneck, 16cyc/wave64
// transcendentals measured in r3 made exp+rcp 80% of VALU time).
// ============================================================================

typedef _Float16 f16x8 __attribute__((ext_vector_type(8)));
typedef float    f32x16 __attribute__((ext_vector_type(16)));
typedef unsigned int u32x4 __attribute__((ext_vector_type(4)));

#define NFRAG  35        // L0: 2, L1..5: 6 each, L6: 3.  1 frag = 64 lanes x 16 B
#define TABN   385       // table entries (384 intervals)
#define TABREP 8         // lane replication
#define TABH   0.025f
#define INVH   40.0f     // 1/TABH
#define TABR   4.8f      // domain [-R, R]
#define UOFF   192.0f    // R/h, exact in f16
#define UMAX   383.999f

// k-slot -> input neuron; -2 = bias (x 1/h), -3 = +192 const, -1 = zero pad
__constant__ int INV[48] = {
     0,  1,  2,  3,   8,  9, 10, 11,   4,  5,  6,  7,  12, 13, 14, 15,
    16, 17, 18, 19,  24, 25, 26, 27,  20, 21, 22, 23,  28, 29, 30, 31,
    32, 33, 34, 35,  -1, -1, -1, -1,  36, 37, 38, 39,  -2, -3, -1, -1 };

__global__ void prep_frags(const float* __restrict__ W0, const float* __restrict__ b0,
                           const float* __restrict__ W1, const float* __restrict__ b1,
                           const float* __restrict__ W2, const float* __restrict__ b2,
                           const float* __restrict__ W3, const float* __restrict__ b3,
                           const float* __restrict__ W4, const float* __restrict__ b4,
                           const float* __restrict__ W5, const float* __restrict__ b5,
                           const float* __restrict__ W6, const float* __restrict__ b6,
                           unsigned short* __restrict__ frags,
                           float2* __restrict__ table)
{
    int tid = blockIdx.x * 256 + threadIdx.x;

    if (tid < NFRAG * 64) {
        int frag = tid >> 6, lane = tid & 63;

        int layer, mt, ch;
        if (frag < 2)       { layer = 0; mt = frag; ch = 0; }
        else if (frag < 32) { int t = frag - 2; layer = 1 + t / 6; int r = t % 6; mt = r / 3; ch = r % 3; }
        else                { layer = 6; mt = 0; ch = frag - 32; }

        const float* Ws[7] = { W0, W1, W2, W3, W4, W5, W6 };
        const float* bs[7] = { b0, b1, b2, b3, b4, b5, b6 };
        const float* W = Ws[layer];
        const float* b = bs[layer];
        const int fout = (layer == 6) ? 3 : 40;
        const float scale = (layer == 6) ? 1.0f : INVH;   // final layer: true output

        int jout  = mt * 32 + (lane & 31);
        int kbase = ch * 16 + (lane >> 5) * 8;

        unsigned short h[8];
        for (int i = 0; i < 8; ++i) {
            int k = kbase + i;
            float v = 0.0f;
            if (jout < fout) {
                int jin;
                if (layer == 0) jin = (k < 3) ? k : ((k == 3) ? -2 : ((k == 4) ? -3 : -1));
                else            jin = INV[k];
                if (jin >= 0)       v = W[jin * fout + jout] * scale;
                else if (jin == -2) v = b[jout] * scale;
                else if (jin == -3) v = (layer == 6) ? 0.0f : UOFF;
            }
            _Float16 hv = (_Float16)v;
            h[i] = __builtin_bit_cast(unsigned short, hv);
        }
        unsigned short* dst = frags + frag * 512 + lane * 8;
        for (int i = 0; i < 8; ++i) dst[i] = h[i];
    }
    else if (tid < NFRAG * 64 + TABN) {
        int i = tid - NFRAG * 64;
        float x  = -TABR + (float)i * TABH;
        float t0 = tanhf(x);
        float t1 = tanhf(x + TABH);
        float2 e = make_float2(t0, t1 - t0);
        for (int r = 0; r < TABREP; ++r) table[i * TABREP + r] = e;
    }
}

__device__ __forceinline__ unsigned int pkf16(float a, float b) {
    return __builtin_bit_cast(unsigned int, __builtin_amdgcn_cvt_pkrtz(a, b));
}
__device__ __forceinline__ f32x16 zf() {
    f32x16 v;
    #pragma unroll
    for (int i = 0; i < 16; ++i) v[i] = 0.0f;
    return v;
}

#define MFMA __builtin_amdgcn_mfma_f32_32x32x16_f16

// D holds table coords u; lookup tanh, pack to next-layer B fragments
#define ACT(Da, Db) do {                              \
    Bf[0]  = pkf16(tl(Da[0]),  tl(Da[1]));            \
    Bf[1]  = pkf16(tl(Da[2]),  tl(Da[3]));            \
    Bf[2]  = pkf16(tl(Da[4]),  tl(Da[5]));            \
    Bf[3]  = pkf16(tl(Da[6]),  tl(Da[7]));            \
    Bf[4]  = pkf16(tl(Da[8]),  tl(Da[9]));            \
    Bf[5]  = pkf16(tl(Da[10]), tl(Da[11]));           \
    Bf[6]  = pkf16(tl(Da[12]), tl(Da[13]));           \
    Bf[7]  = pkf16(tl(Da[14]), tl(Da[15]));           \
    Bf[8]  = pkf16(tl(Db[0]),  tl(Db[1]));            \
    Bf[9]  = pkf16(tl(Db[2]),  tl(Db[3]));            \
    Bf[10] = PK11;                                    \
    Bf[11] = 0u;                                      \
} while (0)

__global__ __launch_bounds__(512) void mlp_mfma(const float* __restrict__ coords,
                                                const unsigned short* __restrict__ frags,
                                                const float2* __restrict__ gtab,
                                                float* __restrict__ out, int npts)
{
    __shared__ __align__(16) unsigned short sf[NFRAG * 512];      // 35840 B
    __shared__ __align__(16) float2 stab[TABN * TABREP];          // 24640 B
    {
        const u32x4* s1 = (const u32x4*)frags; u32x4* d1 = (u32x4*)sf;
        for (int i = threadIdx.x; i < NFRAG * 64; i += 512) d1[i] = s1[i];
        const u32x4* s2 = (const u32x4*)gtab;  u32x4* d2 = (u32x4*)stab;
        for (int i = threadIdx.x; i < TABN * TABREP / 2; i += 512) d2[i] = s2[i];
    }
    __syncthreads();

    const int lane = threadIdx.x & 63;
    const int wid  = threadIdx.x >> 6;
    const int p    = (blockIdx.x * 8 + wid) * 32 + (lane & 31);
    const bool valid = (p < npts);

    float c0 = 0.f, c1 = 0.f, c2 = 0.f;
    if (valid) { c0 = coords[p * 3]; c1 = coords[p * 3 + 1]; c2 = coords[p * 3 + 2]; }

    const unsigned int PK11 = pkf16(1.0f, 1.0f);
    const float2* __restrict__ tb = stab + (lane & (TABREP - 1));   // lane replica base
    const f32x16 CZ = zf();   // hoisted zero-C for MFMA acc init

    // tanh via table: u already = (preact + R)/h from pre-scaled weights
    auto tl = [&](float u) -> float {
        u = __builtin_amdgcn_fmed3f(u, 0.0f, UMAX);
        float fr = __builtin_amdgcn_fractf(u);
        unsigned idx = (unsigned)u;                    // trunc = floor (u >= 0)
        float2 e = tb[idx * TABREP];                   // ds_read_b64
        return __builtin_fmaf(fr, e.y, e.x);
    };

    unsigned int Bf[12];
    Bf[0] = pkf16(c0, c1);
    Bf[1] = pkf16(c2, 1.0f);      // k=3: bias/h column
    Bf[2] = pkf16(1.0f, 0.0f);    // k=4: +192 const column
    Bf[3] = 0u;

    auto AF = [&](int f) -> f16x8 {
        return ((const f16x8*)sf)[f * 64 + lane];
    };
    auto BF = [&](int c) -> f16x8 {
        u32x4 t = { Bf[4 * c + 0], Bf[4 * c + 1], Bf[4 * c + 2], Bf[4 * c + 3] };
        return __builtin_bit_cast(f16x8, t);
    };

    // ---- layer 0 (K chunk 0 only: coords + bias + offset cols)
    {
        f16x8 bb = BF(0);
        f32x16 D0 = MFMA(AF(0), bb, CZ, 0, 0, 0);
        f32x16 D1 = MFMA(AF(1), bb, CZ, 0, 0, 0);
        ACT(D0, D1);
    }

    // ---- hidden layers 1..5
    #pragma unroll
    for (int l = 1; l <= 5; ++l) {
        const int fb = 2 + (l - 1) * 6;
        f16x8 bc0 = BF(0), bc1 = BF(1), bc2 = BF(2);
        f32x16 D0 = MFMA(AF(fb + 0), bc0, CZ, 0, 0, 0);
        D0 = MFMA(AF(fb + 1), bc1, D0, 0, 0, 0);
        D0 = MFMA(AF(fb + 2), bc2, D0, 0, 0, 0);
        f32x16 D1 = MFMA(AF(fb + 3), bc0, CZ, 0, 0, 0);
        D1 = MFMA(AF(fb + 4), bc1, D1, 0, 0, 0);
        D1 = MFMA(AF(fb + 5), bc2, D1, 0, 0, 0);
        ACT(D0, D1);
    }

    // ---- layer 6: [40] -> [3], true scale, no tanh. Outputs rows 0..2.
    {
        f32x16 D0 = MFMA(AF(32), BF(0), CZ, 0, 0, 0);
        D0 = MFMA(AF(33), BF(1), D0, 0, 0, 0);
        D0 = MFMA(AF(34), BF(2), D0, 0, 0, 0);
        if (lane < 32 && valid) {
            out[p * 3 + 0] = D0[0];
            out[p * 3 + 1] = D0[1];
            out[p * 3 + 2] = D0[2];
        }
    }
}

extern "C" void kernel_launch(void* const* d_in, const int* in_sizes, int n_in,
                              void* d_out, int out_size, void* d_ws, size_t ws_size,
                              hipStream_t stream)
{
    const float* coords = (const float*)d_in[0];
    const float* W0 = (const float*)d_in[1];  const float* b0 = (const float*)d_in[2];
    const float* W1 = (const float*)d_in[3];  const float* b1 = (const float*)d_in[4];
    const float* W2 = (const float*)d_in[5];  const float* b2 = (const float*)d_in[6];
    const float* W3 = (const float*)d_in[7];  const float* b3 = (const float*)d_in[8];
    const float* W4 = (const float*)d_in[9];  const float* b4 = (const float*)d_in[10];
    const float* W5 = (const float*)d_in[11]; const float* b5 = (const float*)d_in[12];
    const float* W6 = (const float*)d_in[13]; const float* b6 = (const float*)d_in[14];
    float* out = (float*)d_out;

    unsigned short* frags = (unsigned short*)d_ws;                      // 35840 B
    float2* table = (float2*)((char*)d_ws + NFRAG * 1024);              // 24640 B

    const int npts = in_sizes[0] / 3;

    const int prep_threads = NFRAG * 64 + TABN;
    prep_frags<<<(prep_threads + 255) / 256, 256, 0, stream>>>(
        W0, b0, W1, b1, W2, b2, W3, b3, W4, b4, W5, b5, W6, b6, frags, table);

    const int blocks = (npts + 255) / 256;   // 256 points per block (8 waves x 32)
    mlp_mfma<<<blocks, 512, 0, stream>>>(coords, frags, table, out, npts);
}